// Round 5
// baseline (334.683 us; speedup 1.0000x reference)
//
#include <hip/hip_runtime.h>
#include <hip/hip_bf16.h>
#include <cstdint>

#define DI __device__ __forceinline__

typedef __attribute__((ext_vector_type(4))) float f32x4;
typedef __attribute__((ext_vector_type(8))) short bf16x8;

static constexpr int B_ = 16384, I_ = 1024, H_ = 1024;
static constexpr int M = B_;          // 16384 rows
static constexpr int N = 4 * H_;      // 4096 gate-cols (permuted: see cvt)
static constexpr int K = I_ + H_;     // 2048 ([x | h])
static constexpr int NT = K / 64;     // 32 K-tiles

// workspace layout (bytes)
static constexpr size_t OFF_A  = 0;                         // M*K bf16   (64 MB)
static constexpr size_t OFF_W  = OFF_A + (size_t)M * K * 2; // N*K bf16   (16 MB)
static constexpr size_t OFF_BI = OFF_W + (size_t)N * K * 2; // N f32      (16 KB)

DI unsigned short f2bf(float f) {
    union { float f; unsigned u; } v; v.f = f;
    unsigned r = v.u + 0x7FFFu + ((v.u >> 16) & 1u);
    return (unsigned short)(r >> 16);
}

// ---------------------------------------------------------------- convert
// A' = [x | h] (M x K) bf16. W' rows PERMUTED so that GEMM col
// r = g64*64 + gate*16 + l15 maps to (gate, hcol = g64*16 + l15).
__global__ void cvt_kernel(const float* __restrict__ x, const float* __restrict__ h,
                           const float* __restrict__ Wx, const float* __restrict__ Wh,
                           unsigned short* __restrict__ A, unsigned short* __restrict__ W)
{
    long tid = (long)blockIdx.x * blockDim.x + threadIdx.x;
    long row = tid >> 9;
    int  col = (int)(tid & 511) * 4;
    const float* src;
    unsigned short* dst;
    if (row < M) {
        src = (col < I_) ? x + (size_t)row * I_ + col
                         : h + (size_t)row * H_ + (col - I_);
        dst = A + (size_t)row * K + col;
    } else {
        int r = (int)(row - M);                 // dst row in W'
        int gate = (r >> 4) & 3;
        int hcol = ((r >> 6) << 4) | (r & 15);
        int srow = gate * H_ + hcol;            // src row in [4,H] stack
        src = (col < I_) ? Wx + (size_t)srow * I_ + col
                         : Wh + (size_t)srow * H_ + (col - I_);
        dst = W + (size_t)r * K + col;
    }
    float4 v = *(const float4*)src;
    ushort4 o;
    o.x = f2bf(v.x); o.y = f2bf(v.y); o.z = f2bf(v.z); o.w = f2bf(v.w);
    *(ushort4*)dst = o;
}

__global__ void bias_kernel(const float* __restrict__ bx, const float* __restrict__ bh,
                            float* __restrict__ bias)
{
    int r = blockIdx.x * blockDim.x + threadIdx.x;
    if (r < N) {
        int gate = (r >> 4) & 3;
        int hcol = ((r >> 6) << 4) | (r & 15);
        int s = gate * H_ + hcol;
        bias[r] = bx[s] + bh[s];
    }
}

// ---------------------------------------------------------------- GEMM 256x256
// Rotated 4-phase schedule, one half-tile staged per phase. ONE counted
// s_waitcnt vmcnt(4) per K-tile, placed at END of P4 BEFORE the barrier
// (vmcnt is per-wave; only a pre-barrier wait makes other waves' staged
// data provably visible). The 4 loads left in flight are B0/B1(t+2).
DI void stage_half(const unsigned short* __restrict__ g, int grow0, int kcol,
                   unsigned short* ldsbase, int tid)
{
    const int w    = tid >> 6, lane = tid & 63;
    const int rsub = (w << 3) + (lane >> 3);
    const int kk   = kcol + (((lane & 7) ^ (lane >> 3)) << 3);  // inverse-swizzled src
#pragma unroll
    for (int l = 0; l < 2; ++l) {
        const unsigned short* gp = g + (size_t)(grow0 + (l << 6) + rsub) * K + kk;
        unsigned short* lp = ldsbase + (((l << 6) + (w << 3)) << 6);
        __builtin_amdgcn_global_load_lds(
            (const __attribute__((address_space(1))) void*)gp,
            (__attribute__((address_space(3))) void*)lp, 16, 0, 0);
    }
}

DI bf16x8 ldfrag(const unsigned short* tile, int row, int ks, int lane)
{
    const int sl = ((ks << 2) + (lane >> 4)) ^ (lane & 7);
    return *(const bf16x8*)(tile + (row << 6) + (sl << 3));
}

DI void fbar() {
    __builtin_amdgcn_sched_barrier(0);
    __builtin_amdgcn_s_barrier();
    __builtin_amdgcn_sched_barrier(0);
}

DI float sigf(float v) { return 1.f / (1.f + __expf(-v)); }
DI float tanhfast(float v) {
    float vc = fminf(fmaxf(v, -15.f), 15.f);
    float e  = __expf(2.f * vc);
    return (e - 1.f) / (e + 1.f);
}

#define MFMA_QUAD(MH, N0)                                                     \
  _Pragma("unroll") for (int m_ = 0; m_ < 4; ++m_)                            \
  _Pragma("unroll") for (int dn_ = 0; dn_ < 2; ++dn_)                         \
  _Pragma("unroll") for (int ks_ = 0; ks_ < 2; ++ks_)                         \
    acc[(MH)*4 + m_][(N0) + dn_] = __builtin_amdgcn_mfma_f32_16x16x32_bf16(   \
        a[m_][ks_], b[(N0) + dn_][ks_], acc[(MH)*4 + m_][(N0) + dn_], 0, 0, 0);

__global__ __launch_bounds__(512, 2) void gemm_lstm(
    const unsigned short* __restrict__ Abf, const unsigned short* __restrict__ Wbf,
    const float* __restrict__ bias, const float* __restrict__ c,
    float* __restrict__ out)
{
    __shared__ __align__(16) unsigned short sh[65536];   // 128 KiB

    const int tid  = threadIdx.x;
    const int lane = tid & 63;
    const int wid  = tid >> 6;
    const int wr   = wid >> 2;            // 0..1
    const int wc   = wid & 3;             // 0..3

    const int bid  = blockIdx.x;
    const int wg   = ((bid & 7) << 7) | (bid >> 3);   // XCD swizzle (1024%8==0)
    const int nbk  = wg & 15, mbk = wg >> 4;
    const int brow = mbk << 8, bcol = nbk << 8;

    const int l15  = lane & 15;
    const int rA0  = (wr << 7) + l15;
    const int rB0  = (wc << 6) + l15;

    f32x4 acc[8][4];
#pragma unroll
    for (int i = 0; i < 8; ++i)
#pragma unroll
        for (int j = 0; j < 4; ++j) acc[i][j] = f32x4{0.f, 0.f, 0.f, 0.f};
    bf16x8 a[4][2], b[4][2];

    // prologue: buf0 complete (8 loads) + buf1 B halves (4 loads).
    // vmcnt(4) BEFORE the barrier: tile0 landed + visible; B(1) flying.
    {
        unsigned short* A0 = sh;
        unsigned short* B0 = sh + 16384;
        unsigned short* B1 = sh + 32768 + 16384;
        stage_half(Abf, brow,       0, A0,        tid);   // AH0(0)
        stage_half(Abf, brow + 128, 0, A0 + 8192, tid);   // AH1(0)
        stage_half(Wbf, bcol,       0, B0,        tid);   // BH0(0)
        stage_half(Wbf, bcol + 128, 0, B0 + 8192, tid);   // BH1(0)
        stage_half(Wbf, bcol,      64, B1,        tid);   // BH0(1)
        stage_half(Wbf, bcol + 128,64, B1 + 8192, tid);   // BH1(1)
        asm volatile("s_waitcnt vmcnt(4)" ::: "memory");
        fbar();
    }

    for (int t = 0; t < NT; ++t) {
        const int q = t & 1;
        unsigned short* curA = sh + q * 32768;
        unsigned short* curB = curA + 16384;
        unsigned short* oA   = sh + (q ^ 1) * 32768;      // A buf for t+1
        const int k1 = ((t + 1) & 31) << 6;
        const int k2 = ((t + 2) & 31) << 6;

        // ---- P1: stage AH0(t+1); read A mf0-3 + B n0,n1 (landed per
        // the pre-barrier wait at P4(t-1)).
        stage_half(Abf, brow, k1, oA, tid);
#pragma unroll
        for (int m = 0; m < 4; ++m)
#pragma unroll
            for (int ks = 0; ks < 2; ++ks)
                a[m][ks] = ldfrag(curA, rA0 + m * 16, ks, lane);
#pragma unroll
        for (int n = 0; n < 2; ++n)
#pragma unroll
            for (int ks = 0; ks < 2; ++ks)
                b[n][ks] = ldfrag(curB, rB0 + n * 16, ks, lane);
        fbar();
        __builtin_amdgcn_s_setprio(1);
        MFMA_QUAD(0, 0);
        __builtin_amdgcn_s_setprio(0);
        fbar();

        // ---- P2: stage AH1(t+1); read B n2,n3
        stage_half(Abf, brow + 128, k1, oA + 8192, tid);
#pragma unroll
        for (int n = 2; n < 4; ++n)
#pragma unroll
            for (int ks = 0; ks < 2; ++ks)
                b[n][ks] = ldfrag(curB, rB0 + n * 16, ks, lane);
        fbar();
        __builtin_amdgcn_s_setprio(1);
        MFMA_QUAD(0, 2);
        __builtin_amdgcn_s_setprio(0);
        fbar();

        // ---- P3: stage BH0(t+2) into cur (B reads done after P2); read A mf4-7
        stage_half(Wbf, bcol, k2, curB, tid);
#pragma unroll
        for (int m = 0; m < 4; ++m)
#pragma unroll
            for (int ks = 0; ks < 2; ++ks)
                a[m][ks] = ldfrag(curA, rA0 + 64 + m * 16, ks, lane);
        fbar();
        __builtin_amdgcn_s_setprio(1);
        MFMA_QUAD(1, 2);
        __builtin_amdgcn_s_setprio(0);
        fbar();

        // ---- P4: stage BH1(t+2); COUNTED WAIT PRE-BARRIER: all loads
        // through AH1(t+1) landed; B0/B1(t+2) (4 loads) stay in flight.
        stage_half(Wbf, bcol + 128, k2, curB + 8192, tid);
        asm volatile("s_waitcnt vmcnt(4)" ::: "memory");
        fbar();
        __builtin_amdgcn_s_setprio(1);
        MFMA_QUAD(1, 0);
        __builtin_amdgcn_s_setprio(0);
        fbar();
    }

    // drain stragglers before LDS lifetime ends / epilogue
    asm volatile("s_waitcnt vmcnt(0)" ::: "memory");

    // ---- fused LSTM epilogue: n-index = gate for one h-col per lane
    const int hcol  = (((nbk << 2) + wc) << 4) + l15;
    const int crow0 = brow + (wr << 7) + ((lane >> 4) << 2);
    const int cb0   = bcol + (wc << 6) + l15;
    const float bs0 = bias[cb0];
    const float bs1 = bias[cb0 + 16];
    const float bs2 = bias[cb0 + 32];
    const float bs3 = bias[cb0 + 48];
    const size_t P  = (size_t)B_ * H_;
#pragma unroll
    for (int mf = 0; mf < 8; ++mf) {
#pragma unroll
        for (int j = 0; j < 4; ++j) {
            const int row = crow0 + mf * 16 + j;
            const size_t base = (size_t)row * H_ + hcol;
            float fg = sigf(acc[mf][0][j] + bs0);
            float ig = sigf(acc[mf][1][j] + bs1);
            float kg = tanhfast(acc[mf][2][j] + bs2);
            float og = sigf(acc[mf][3][j] + bs3);
            float cv = c[base];
            float cn = fg * cv + ig * kg;
            float hn = og * tanhfast(cn);
            out[base]         = og;
            out[P + base]     = cn;
            out[2 * P + base] = hn;
        }
    }
}

// ---------------------------------------------------------------- launch
extern "C" void kernel_launch(void* const* d_in, const int* in_sizes, int n_in,
                              void* d_out, int out_size, void* d_ws, size_t ws_size,
                              hipStream_t stream)
{
    const float* x  = (const float*)d_in[0];
    const float* c  = (const float*)d_in[1];
    const float* h  = (const float*)d_in[2];
    const float* Wx = (const float*)d_in[3];
    const float* bx = (const float*)d_in[4];
    const float* Wh = (const float*)d_in[5];
    const float* bh = (const float*)d_in[6];

    unsigned short* Abf  = (unsigned short*)((char*)d_ws + OFF_A);
    unsigned short* Wbf  = (unsigned short*)((char*)d_ws + OFF_W);
    float*          bias = (float*)((char*)d_ws + OFF_BI);
    float*          out  = (float*)d_out;

    cvt_kernel<<<40960, 256, 0, stream>>>(x, h, Wx, Wh, Abf, Wbf);
    bias_kernel<<<16, 256, 0, stream>>>(bx, bh, bias);
    gemm_lstm<<<(M / 256) * (N / 256), 512, 0, stream>>>(
        Abf, Wbf, bias, c, out);
}

// Round 6
// 334.413 us; speedup vs baseline: 1.0008x; 1.0008x over previous
//
#include <hip/hip_runtime.h>
#include <hip/hip_bf16.h>
#include <cstdint>

#define DI __device__ __forceinline__

typedef __attribute__((ext_vector_type(4))) float f32x4;
typedef __attribute__((ext_vector_type(8))) short bf16x8;

static constexpr int B_ = 16384, I_ = 1024, H_ = 1024;
static constexpr int M = B_;          // 16384 rows
static constexpr int N = 4 * H_;      // 4096 gate-cols (permuted: see cvt)
static constexpr int K = I_ + H_;     // 2048 ([x | h])
static constexpr int NT = K / 64;     // 32 K-tiles

// workspace layout (bytes)
static constexpr size_t OFF_A  = 0;                         // M*K bf16   (64 MB)
static constexpr size_t OFF_W  = OFF_A + (size_t)M * K * 2; // N*K bf16   (16 MB)
static constexpr size_t OFF_BI = OFF_W + (size_t)N * K * 2; // N f32      (16 KB)

DI unsigned short f2bf(float f) {
    union { float f; unsigned u; } v; v.f = f;
    unsigned r = v.u + 0x7FFFu + ((v.u >> 16) & 1u);
    return (unsigned short)(r >> 16);
}

// ---------------------------------------------------------------- convert
// A' = [x | h] (M x K) bf16. W' rows PERMUTED so that GEMM col
// r = g64*64 + gate*16 + l15 maps to (gate, hcol = g64*16 + l15).
__global__ void cvt_kernel(const float* __restrict__ x, const float* __restrict__ h,
                           const float* __restrict__ Wx, const float* __restrict__ Wh,
                           unsigned short* __restrict__ A, unsigned short* __restrict__ W)
{
    long tid = (long)blockIdx.x * blockDim.x + threadIdx.x;
    long row = tid >> 9;
    int  col = (int)(tid & 511) * 4;
    const float* src;
    unsigned short* dst;
    if (row < M) {
        src = (col < I_) ? x + (size_t)row * I_ + col
                         : h + (size_t)row * H_ + (col - I_);
        dst = A + (size_t)row * K + col;
    } else {
        int r = (int)(row - M);                 // dst row in W'
        int gate = (r >> 4) & 3;
        int hcol = ((r >> 6) << 4) | (r & 15);
        int srow = gate * H_ + hcol;            // src row in [4,H] stack
        src = (col < I_) ? Wx + (size_t)srow * I_ + col
                         : Wh + (size_t)srow * H_ + (col - I_);
        dst = W + (size_t)r * K + col;
    }
    float4 v = *(const float4*)src;
    ushort4 o;
    o.x = f2bf(v.x); o.y = f2bf(v.y); o.z = f2bf(v.z); o.w = f2bf(v.w);
    *(ushort4*)dst = o;
}

__global__ void bias_kernel(const float* __restrict__ bx, const float* __restrict__ bh,
                            float* __restrict__ bias)
{
    int r = blockIdx.x * blockDim.x + threadIdx.x;
    if (r < N) {
        int gate = (r >> 4) & 3;
        int hcol = ((r >> 6) << 4) | (r & 15);
        int s = gate * H_ + hcol;
        bias[r] = bx[s] + bh[s];
    }
}

// ---------------------------------------------------------------- GEMM 256x256
// 4-phase schedule with DEEP staging rotation: P1 stages AH1(t+1);
// P3 stages BH0(t+2); P4 stages BH1(t+2) + AH0(t+2). Single counted
// s_waitcnt vmcnt(6) per K-tile at END of P4, BEFORE the barrier (vmcnt is
// per-wave; pre-barrier wait publishes all waves' staged data). In-flight
// across the barrier: the 3 half-tiles staged in P3/P4 (6 loads). The
// youngest load the wait must cover (AH1(t+1), issued P1) is 3 phases old.
DI void stage_half(const unsigned short* __restrict__ g, int grow0, int kcol,
                   unsigned short* ldsbase, int tid)
{
    const int w    = tid >> 6, lane = tid & 63;
    const int rsub = (w << 3) + (lane >> 3);
    const int kk   = kcol + (((lane & 7) ^ (lane >> 3)) << 3);  // inverse-swizzled src
#pragma unroll
    for (int l = 0; l < 2; ++l) {
        const unsigned short* gp = g + (size_t)(grow0 + (l << 6) + rsub) * K + kk;
        unsigned short* lp = ldsbase + (((l << 6) + (w << 3)) << 6);
        __builtin_amdgcn_global_load_lds(
            (const __attribute__((address_space(1))) void*)gp,
            (__attribute__((address_space(3))) void*)lp, 16, 0, 0);
    }
}

DI bf16x8 ldfrag(const unsigned short* tile, int row, int ks, int lane)
{
    const int sl = ((ks << 2) + (lane >> 4)) ^ (lane & 7);
    return *(const bf16x8*)(tile + (row << 6) + (sl << 3));
}

DI void fbar() {
    __builtin_amdgcn_sched_barrier(0);
    __builtin_amdgcn_s_barrier();
    __builtin_amdgcn_sched_barrier(0);
}

DI float sigf(float v) { return 1.f / (1.f + __expf(-v)); }
DI float tanhfast(float v) {
    float vc = fminf(fmaxf(v, -15.f), 15.f);
    float e  = __expf(2.f * vc);
    return (e - 1.f) / (e + 1.f);
}

// ks OUTERMOST: 8 independent MFMAs between accumulator reuses (reuse
// distance 8 instead of 2 -> dependent-issue stalls hidden).
#define MFMA_QUAD(MH, N0)                                                     \
  _Pragma("unroll") for (int ks_ = 0; ks_ < 2; ++ks_)                         \
  _Pragma("unroll") for (int m_ = 0; m_ < 4; ++m_)                            \
  _Pragma("unroll") for (int dn_ = 0; dn_ < 2; ++dn_)                         \
    acc[(MH)*4 + m_][(N0) + dn_] = __builtin_amdgcn_mfma_f32_16x16x32_bf16(   \
        a[m_][ks_], b[(N0) + dn_][ks_], acc[(MH)*4 + m_][(N0) + dn_], 0, 0, 0);

__global__ __launch_bounds__(512, 2) void gemm_lstm(
    const unsigned short* __restrict__ Abf, const unsigned short* __restrict__ Wbf,
    const float* __restrict__ bias, const float* __restrict__ c,
    float* __restrict__ out)
{
    __shared__ __align__(16) unsigned short sh[65536];   // 128 KiB

    const int tid  = threadIdx.x;
    const int lane = tid & 63;
    const int wid  = tid >> 6;
    const int wr   = wid >> 2;            // 0..1
    const int wc   = wid & 3;             // 0..3

    const int bid  = blockIdx.x;
    const int wg   = ((bid & 7) << 7) | (bid >> 3);   // XCD swizzle (1024%8==0)
    const int nbk  = wg & 15, mbk = wg >> 4;
    const int brow = mbk << 8, bcol = nbk << 8;

    const int l15  = lane & 15;
    const int rA0  = (wr << 7) + l15;
    const int rB0  = (wc << 6) + l15;

    f32x4 acc[8][4];
#pragma unroll
    for (int i = 0; i < 8; ++i)
#pragma unroll
        for (int j = 0; j < 4; ++j) acc[i][j] = f32x4{0.f, 0.f, 0.f, 0.f};
    bf16x8 a[4][2], b[4][2];

    // prologue: tile0 complete (8 loads) + B(1) both halves + AH0(1)
    // (6 loads in flight after the wait -- steady-state invariant).
    {
        unsigned short* A0 = sh;
        unsigned short* B0 = sh + 16384;
        unsigned short* A1 = sh + 32768;
        unsigned short* B1 = sh + 32768 + 16384;
        stage_half(Abf, brow,       0, A0,        tid);   // AH0(0)
        stage_half(Abf, brow + 128, 0, A0 + 8192, tid);   // AH1(0)
        stage_half(Wbf, bcol,       0, B0,        tid);   // BH0(0)
        stage_half(Wbf, bcol + 128, 0, B0 + 8192, tid);   // BH1(0)
        stage_half(Wbf, bcol,      64, B1,        tid);   // BH0(1)
        stage_half(Wbf, bcol + 128,64, B1 + 8192, tid);   // BH1(1)
        stage_half(Abf, brow,      64, A1,        tid);   // AH0(1)
        asm volatile("s_waitcnt vmcnt(6)" ::: "memory");
        fbar();
    }

    for (int t = 0; t < NT; ++t) {
        const int q = t & 1;
        unsigned short* curA = sh + q * 32768;
        unsigned short* curB = curA + 16384;
        unsigned short* oA   = sh + (q ^ 1) * 32768;      // A buf for t+1
        const int k1 = ((t + 1) & 31) << 6;
        const int k2 = ((t + 2) & 31) << 6;

        // ---- P1: stage AH1(t+1) (oA rows 128-255, freed P3(t-1));
        // read A mf0-3 + B n0,n1; MFMA (mh0, n01).
        stage_half(Abf, brow + 128, k1, oA + 8192, tid);
#pragma unroll
        for (int m = 0; m < 4; ++m)
#pragma unroll
            for (int ks = 0; ks < 2; ++ks)
                a[m][ks] = ldfrag(curA, rA0 + m * 16, ks, lane);
#pragma unroll
        for (int n = 0; n < 2; ++n)
#pragma unroll
            for (int ks = 0; ks < 2; ++ks)
                b[n][ks] = ldfrag(curB, rB0 + n * 16, ks, lane);
        fbar();
        __builtin_amdgcn_s_setprio(1);
        MFMA_QUAD(0, 0);
        __builtin_amdgcn_s_setprio(0);
        fbar();

        // ---- P2: read B n2,n3; MFMA (mh0, n23)
#pragma unroll
        for (int n = 2; n < 4; ++n)
#pragma unroll
            for (int ks = 0; ks < 2; ++ks)
                b[n][ks] = ldfrag(curB, rB0 + n * 16, ks, lane);
        fbar();
        __builtin_amdgcn_s_setprio(1);
        MFMA_QUAD(0, 2);
        __builtin_amdgcn_s_setprio(0);
        fbar();

        // ---- P3: stage BH0(t+2) (curB rows 0-127, B reads done after P2);
        // read A mf4-7; MFMA (mh1, n23)
        stage_half(Wbf, bcol, k2, curB, tid);
#pragma unroll
        for (int m = 0; m < 4; ++m)
#pragma unroll
            for (int ks = 0; ks < 2; ++ks)
                a[m][ks] = ldfrag(curA, rA0 + 64 + m * 16, ks, lane);
        fbar();
        __builtin_amdgcn_s_setprio(1);
        MFMA_QUAD(1, 2);
        __builtin_amdgcn_s_setprio(0);
        fbar();

        // ---- P4: stage BH1(t+2) + AH0(t+2) (curA rows 0-127, freed after
        // P1's reads); COUNTED WAIT vmcnt(6) PRE-BARRIER: everything through
        // AH1(t+1) landed; the 3 half-tiles staged P3/P4 stay in flight.
        stage_half(Wbf, bcol + 128, k2, curB + 8192, tid);
        stage_half(Abf, brow, k2, curA, tid);
        asm volatile("s_waitcnt vmcnt(6)" ::: "memory");
        fbar();
        __builtin_amdgcn_s_setprio(1);
        MFMA_QUAD(1, 0);
        __builtin_amdgcn_s_setprio(0);
        fbar();
    }

    // drain stragglers before LDS lifetime ends / epilogue
    asm volatile("s_waitcnt vmcnt(0)" ::: "memory");

    // ---- fused LSTM epilogue: n-index = gate for one h-col per lane.
    // Nontemporal out-stores / c-load: keep A/W resident in L2/L3.
    const int hcol  = (((nbk << 2) + wc) << 4) + l15;
    const int crow0 = brow + (wr << 7) + ((lane >> 4) << 2);
    const int cb0   = bcol + (wc << 6) + l15;
    const float bs0 = bias[cb0];
    const float bs1 = bias[cb0 + 16];
    const float bs2 = bias[cb0 + 32];
    const float bs3 = bias[cb0 + 48];
    const size_t P  = (size_t)B_ * H_;
#pragma unroll
    for (int mf = 0; mf < 8; ++mf) {
#pragma unroll
        for (int j = 0; j < 4; ++j) {
            const int row = crow0 + mf * 16 + j;
            const size_t base = (size_t)row * H_ + hcol;
            float fg = sigf(acc[mf][0][j] + bs0);
            float ig = sigf(acc[mf][1][j] + bs1);
            float kg = tanhfast(acc[mf][2][j] + bs2);
            float og = sigf(acc[mf][3][j] + bs3);
            float cv = __builtin_nontemporal_load(c + base);
            float cn = fg * cv + ig * kg;
            float hn = og * tanhfast(cn);
            __builtin_nontemporal_store(og, out + base);
            __builtin_nontemporal_store(cn, out + P + base);
            __builtin_nontemporal_store(hn, out + 2 * P + base);
        }
    }
}

// ---------------------------------------------------------------- launch
extern "C" void kernel_launch(void* const* d_in, const int* in_sizes, int n_in,
                              void* d_out, int out_size, void* d_ws, size_t ws_size,
                              hipStream_t stream)
{
    const float* x  = (const float*)d_in[0];
    const float* c  = (const float*)d_in[1];
    const float* h  = (const float*)d_in[2];
    const float* Wx = (const float*)d_in[3];
    const float* bx = (const float*)d_in[4];
    const float* Wh = (const float*)d_in[5];
    const float* bh = (const float*)d_in[6];

    unsigned short* Abf  = (unsigned short*)((char*)d_ws + OFF_A);
    unsigned short* Wbf  = (unsigned short*)((char*)d_ws + OFF_W);
    float*          bias = (float*)((char*)d_ws + OFF_BI);
    float*          out  = (float*)d_out;

    cvt_kernel<<<40960, 256, 0, stream>>>(x, h, Wx, Wh, Abf, Wbf);
    bias_kernel<<<16, 256, 0, stream>>>(bx, bh, bias);
    gemm_lstm<<<(M / 256) * (N / 256), 512, 0, stream>>>(
        Abf, Wbf, bias, c, out);
}